// Round 9
// baseline (185.233 us; speedup 1.0000x reference)
//
#include <hip/hip_runtime.h>
#include <hip/hip_bf16.h>
#include <math.h>

// TreeLSTM, B=8, L=4096, D=300, H=128, 12 levels. Round 15:
// - R14 confirmed weight-amortization theory (169.1us). This round:
//   (a) lev3 nst=2 (same lever, 256 blocks still full GPU).
//   (b) levels 6..8 fused into ONE 4-block tail3 kernel in the R10-proven
//       512-thr/8-wave shape (wave = h-group, Wfr once at kernel scope ->
//       residency law respected). LDS 160 KB: Als 64 (reused as h7+c7 after
//       lev6) + h6 32 + c6 64. Swizzle/fragment formulas byte-identical to
//       R10 fused2 (correctness-proven) and finish. 8 dispatches total.
// - leaf (reorder fold + on-the-fly W_leaf convert), level_ws+nst, finish:
//   unchanged R14 (known good).

typedef __attribute__((ext_vector_type(8))) short bfrag8;   // 8 bf16 = 4 VGPRs
typedef __attribute__((ext_vector_type(4))) float f32x4;

__device__ __forceinline__ float rcpf(float x) { return __builtin_amdgcn_rcpf(x); }
__device__ __forceinline__ float sigf(float x) { return rcpf(1.0f + __expf(-x)); }
__device__ __forceinline__ float tanh_f(float x) {
    float e = __expf(2.0f * x);              // x>>0: e=inf -> rcp=0 -> 1 ; x<<0: e=0 -> -1
    return 1.0f - 2.0f * rcpf(e + 1.0f);
}
__device__ __forceinline__ short f2bf(float f) {
    __hip_bfloat16 h = __float2bfloat16(f);
    return *reinterpret_cast<short*>(&h);
}
__device__ __forceinline__ bfrag8 pack8(f32x4 a, f32x4 b) {
    union { int i[4]; bfrag8 v; } u;
    asm("v_cvt_pk_bf16_f32 %0, %1, %2" : "=v"(u.i[0]) : "v"(a[0]), "v"(a[1]));
    asm("v_cvt_pk_bf16_f32 %0, %1, %2" : "=v"(u.i[1]) : "v"(a[2]), "v"(a[3]));
    asm("v_cvt_pk_bf16_f32 %0, %1, %2" : "=v"(u.i[2]) : "v"(b[0]), "v"(b[1]));
    asm("v_cvt_pk_bf16_f32 %0, %1, %2" : "=v"(u.i[3]) : "v"(b[2]), "v"(b[3]));
    return u.v;
}
#define GLDS(gp, lp) __builtin_amdgcn_global_load_lds( \
    (const __attribute__((address_space(1))) void*)(gp), \
    (__attribute__((address_space(3))) void*)(lp), 16, 0, 0)

// ---------------- leaf: [32768,320fp32]@[320,256] + bias, split h/c ----------------
__global__ __launch_bounds__(256) void leaf_kernel(
    const float* __restrict__ x,     const float* __restrict__ Wleaf,
    const float* __restrict__ W_l,   const float* __restrict__ W_r,
    const float* __restrict__ bleaf,
    short* __restrict__ hD,       // level-1 A, chunk layout [32][16384] units
    float* __restrict__ cD,       // [32768][128] fp32
    short* __restrict__ Wcat_ch)  // [32][640] chunk units (for later levels)
{
    __shared__ float Als[128 * 64];     // 32 KB: [row][16 units of 4 floats], swizzled
    __shared__ short Bls[8 * 128 * 8];  // 16 KB: [c][n] units
    const int tid  = threadIdx.x;
    const int w    = tid >> 6, lane = tid & 63;
    const int quad = lane >> 4, l16 = lane & 15;
    const int mBlk = blockIdx.x * 128, nBlk = blockIdx.y * 128;
    const int waveM = (w >> 1) * 64, waveN = (w & 1) * 64;

    // ---- folded reorder: WcatC (163840 elems over 160 blocks x 1024) ----
    if (blockIdx.y == 0 && blockIdx.x < 160) {
        #pragma unroll
        for (int e = 0; e < 4; ++e) {
            int idx = blockIdx.x * 1024 + e * 256 + tid;
            int n = idx >> 8, k = idx & 255;
            float v = (k < 128) ? W_l[k * 640 + n] : W_r[(k - 128) * 640 + n];
            Wcat_ch[(((size_t)(k >> 3)) * 640 + n) * 8 + (k & 7)] = f2bf(v);
        }
    }

    f32x4 acc[4][4] = {};
    const f32x4 zero4 = {0.f, 0.f, 0.f, 0.f};

    for (int c = 0; c < 5; ++c) {           // K = 5 * 64 = 320 (300 + zero pad)
        const int k0c = c * 64;
        // ---- stage A (x) as fp32, XOR-swizzled source, linear LDS ----
        {
            const int q_lds = lane & 15;
            const int rsub  = lane >> 4;
            #pragma unroll
            for (int g = 0; g < 8; ++g) {
                int row = w * 32 + g * 4 + rsub;
                int q_g = (q_lds & 8) | ((q_lds & 7) ^ (row & 7));
                if (c < 4 || q_g < 11) {
                    GLDS(x + (size_t)(mBlk + row) * 300 + k0c + q_g * 4,
                         (char*)Als + (w * 32 + g * 4) * 256);
                } else {
                    *(f32x4*)((char*)Als + row * 256 + q_lds * 16) = zero4;  // pad k=300..319
                }
            }
        }
        // ---- stage B on the fly from W_leaf fp32 (1024 units, 4/thread) ----
        #pragma unroll
        for (int uu = 0; uu < 4; ++uu) {
            int id  = uu * 256 + tid;
            int ccl = id >> 7, nl = id & 127;   // chunk-in-iter [0,8), col [0,128)
            int k0  = (c * 8 + ccl) * 8;
            int n   = nBlk + nl;
            f32x4 v0, v1;
            #pragma unroll
            for (int jj = 0; jj < 4; ++jj)
                v0[jj] = (k0 + jj < 300) ? Wleaf[(size_t)(k0 + jj) * 256 + n] : 0.0f;
            #pragma unroll
            for (int jj = 0; jj < 4; ++jj)
                v1[jj] = (k0 + 4 + jj < 300) ? Wleaf[(size_t)(k0 + 4 + jj) * 256 + n] : 0.0f;
            *(bfrag8*)(Bls + (ccl * 128 + nl) * 8) = pack8(v0, v1);
        }
        __syncthreads();
        #pragma unroll
        for (int ks = 0; ks < 2; ++ks) {
            const int ca = ks * 4 + quad;
            bfrag8 af[4], bf4[4];
            #pragma unroll
            for (int i = 0; i < 4; ++i) {
                int r  = waveM + i * 16 + l16;
                int u0 = 2 * ca, u1 = 2 * ca + 1;
                int s0 = (u0 & 8) | ((u0 & 7) ^ (r & 7));
                int s1 = (u1 & 8) | ((u1 & 7) ^ (r & 7));
                f32x4 a0 = *(const f32x4*)(Als + r * 64 + s0 * 4);
                f32x4 a1 = *(const f32x4*)(Als + r * 64 + s1 * 4);
                af[i] = pack8(a0, a1);
            }
            #pragma unroll
            for (int jn = 0; jn < 4; ++jn)
                bf4[jn] = *(const bfrag8*)(Bls + (ca * 128 + waveN + jn * 16 + l16) * 8);
            #pragma unroll
            for (int i = 0; i < 4; ++i)
                #pragma unroll
                for (int jn = 0; jn < 4; ++jn)
                    acc[i][jn] = __builtin_amdgcn_mfma_f32_16x16x32_bf16(
                                     af[i], bf4[jn], acc[i][jn], 0, 0, 0);
        }
        __syncthreads();
    }

    #pragma unroll
    for (int i = 0; i < 4; ++i) {
        int row0 = mBlk + waveM + i * 16 + quad * 4;
        #pragma unroll
        for (int jn = 0; jn < 4; ++jn) {
            int col = nBlk + waveN + jn * 16 + l16;
            float bv = bleaf[col];
            #pragma unroll
            for (int rg = 0; rg < 4; ++rg) {
                float v = acc[i][jn][rg] + bv;
                int m = row0 + rg;
                if (nBlk == 0) {
                    int hc = col;
                    hD[(((size_t)((m & 1) * 16 + (hc >> 3))) * 16384 + (m >> 1)) * 8
                       + (hc & 7)] = f2bf(v);
                } else {
                    cD[(size_t)m * 128 + (col - 128)] = v;
                }
            }
        }
    }
}

// ---------------- weight-stationary level kernel (levels 1..5) ----------------
// PROVEN SHAPE: Wfr loaded ONCE at kernel scope. nst row-subtiles amortize.
__global__ __launch_bounds__(256, 2) void level_ws_kernel(
    const short* __restrict__ A,      // [32][M] chunk units
    const float* __restrict__ cprev,  // [2M][128] fp32
    const short* __restrict__ Wch,    // [32][640] chunk units
    const float* __restrict__ bias,   // [640]
    short* __restrict__ hout, float* __restrict__ cout_,
    int M, int nst)
{
    __shared__ short Als[32 * 64 * 8];   // 32 KB, [c][row]
    const int tid  = threadIdx.x;
    const int w    = tid >> 6, lane = tid & 63;
    const int quad = lane >> 4, l16 = lane & 15;
    const int j   = blockIdx.y;
    const int tb0 = blockIdx.x * 64 * nst;
    const int h   = j * 16 + l16;

    // stage subtile 0 (overlaps the Wfr loads below)
    #pragma unroll
    for (int s = 0; s < 8; ++s)
        GLDS(A + ((size_t)(s * 4 + w) * M + tb0 + lane) * 8,
             (char*)Als + (s * 4 + w) * 1024);

    bfrag8 Wfr[5][8];
    #pragma unroll
    for (int g = 0; g < 5; ++g)
        #pragma unroll
        for (int s = 0; s < 8; ++s)
            Wfr[g][s] = *(const bfrag8*)(Wch + ((size_t)(s * 4 + quad) * 640
                                                + g * 128 + h) * 8);
    const float bi  = bias[h],       bfl = bias[128 + h], bfr_ = bias[256 + h];
    const float bo  = bias[384 + h], bg  = bias[512 + h];

    const int Mn = M >> 1;
    for (int st = 0; st < nst; ++st) {
        const int tb = tb0 + st * 64;
        __syncthreads();                 // staging of subtile st complete

        f32x4 acc[5] = {};
        #pragma unroll
        for (int s = 0; s < 8; ++s) {
            bfrag8 af = *(const bfrag8*)(Als + ((s * 4 + quad) * 64 + w * 16 + l16) * 8);
            #pragma unroll
            for (int g = 0; g < 5; ++g)
                acc[g] = __builtin_amdgcn_mfma_f32_16x16x32_bf16(af, Wfr[g][s], acc[g], 0, 0, 0);
        }

        if (st + 1 < nst) {
            __syncthreads();             // all Als reads done; restage
            #pragma unroll
            for (int s = 0; s < 8; ++s)
                GLDS(A + ((size_t)(s * 4 + w) * M + tb + 64 + lane) * 8,
                     (char*)Als + (s * 4 + w) * 1024);
        }

        #pragma unroll
        for (int rg = 0; rg < 4; ++rg) {
            int m = tb + w * 16 + quad * 4 + rg;
            float gi  = acc[0][rg] + bi;
            float gfl = acc[1][rg] + bfl;
            float gfr = acc[2][rg] + bfr_;
            float go  = acc[3][rg] + bo;
            float gg  = acc[4][rg] + bg;
            float cl  = cprev[(size_t)(2 * m) * 128 + h];
            float cr  = cprev[(size_t)(2 * m + 1) * 128 + h];
            float cn  = sigf(gfl) * cl + sigf(gfr) * cr + sigf(gi) * tanh_f(gg);
            float hn  = sigf(go) * tanh_f(cn);
            hout[(((size_t)((m & 1) * 16 + (h >> 3))) * Mn + (m >> 1)) * 8
                 + (h & 7)] = f2bf(hn);
            cout_[(size_t)m * 128 + h] = cn;
        }
    }
}

// ---------------- tail3: levels 6,7,8 in one 4-block dispatch ----------------
// R10-proven shape: 512 thr, 8 waves = 8 h-groups, Wfr once at kernel scope,
// __launch_bounds__(512,2). Block b owns lev6 rows [128b,128b+128) -> lev7
// [64b..) -> lev8 [32b..). LDS 160 KB: Als 64 (A stage; reused as h7 16 +
// c7 32 after lev6) + h6 32 (swizzled) + c6 64. Syncs between levels only.
__global__ __launch_bounds__(512, 2) void tail3_kernel(
    const short* __restrict__ A,      // [32][512] units (lev6 input h)
    const float* __restrict__ cprev,  // [1024][128] fp32 (lev6 input c)
    const short* __restrict__ Wch, const float* __restrict__ bias,
    short* __restrict__ hout,         // lev8 h: [32][64] units (Mn=64)
    float* __restrict__ cout_)        // lev8 c: [128][128] fp32
{
    __shared__ short Als[32 * 128 * 8];   // 64 KB: A stage, then h7+c7
    __shared__ short h6 [128 * 128];      // 32 KB: lev6 h image (swizzled)
    __shared__ float c6 [128 * 128];      // 64 KB: lev6 c
    const int tid  = threadIdx.x;
    const int w    = tid >> 6, lane = tid & 63;
    const int quad = lane >> 4, l16 = lane & 15;
    const int h    = w * 16 + l16;        // wave = h-group
    const int b    = blockIdx.x;          // 4 blocks

    // stage A: 64 KB = 64 GLDS (8/wave); unit idx: chunk cg=idx>>1, half=idx&1
    #pragma unroll
    for (int s = 0; s < 8; ++s) {
        int idx = s * 8 + w;
        GLDS(A + ((size_t)(idx >> 1) * 512 + b * 128 + (idx & 1) * 64 + lane) * 8,
             (char*)Als + idx * 1024);
    }

    bfrag8 Wfr[5][8];
    #pragma unroll
    for (int g = 0; g < 5; ++g)
        #pragma unroll
        for (int s = 0; s < 8; ++s)
            Wfr[g][s] = *(const bfrag8*)(Wch + ((size_t)(s * 4 + quad) * 640
                                                + g * 128 + h) * 8);
    const float bi  = bias[h],       bfl = bias[128 + h], bfr_ = bias[256 + h];
    const float bo  = bias[384 + h], bg  = bias[512 + h];

    __syncthreads();

    // ---- lev6: 128 rows (A from Als, c from global) ----
    for (int rt = 0; rt < 8; ++rt) {
        f32x4 acc[5] = {};
        #pragma unroll
        for (int s = 0; s < 8; ++s) {
            bfrag8 af = *(const bfrag8*)(Als + ((s * 4 + quad) * 128
                                                + rt * 16 + l16) * 8);
            #pragma unroll
            for (int g = 0; g < 5; ++g)
                acc[g] = __builtin_amdgcn_mfma_f32_16x16x32_bf16(
                             af, Wfr[g][s], acc[g], 0, 0, 0);
        }
        #pragma unroll
        for (int rg = 0; rg < 4; ++rg) {
            int mloc = rt * 16 + quad * 4 + rg;      // [0,128)
            int mG   = b * 128 + mloc;
            float gi  = acc[0][rg] + bi;
            float gfl = acc[1][rg] + bfl;
            float gfr = acc[2][rg] + bfr_;
            float go  = acc[3][rg] + bo;
            float gg  = acc[4][rg] + bg;
            float cl  = cprev[(size_t)(2 * mG) * 128 + h];
            float cr  = cprev[(size_t)(2 * mG + 1) * 128 + h];
            float cn  = sigf(gfl) * cl + sigf(gfr) * cr + sigf(gi) * tanh_f(gg);
            float hn  = sigf(go) * tanh_f(cn);
            c6[mloc * 128 + h] = cn;
            int byte = (mloc * 256 + h * 2) ^ (((mloc >> 1) & 7) << 4);
            *(short*)((char*)h6 + byte) = f2bf(hn);
        }
    }
    __syncthreads();   // Als dead (all lev6 MFMA reads done); h6/c6 complete

    // ---- lev7: 64 rows (h from h6, c from c6); h7/c7 overlay Als ----
    short* h7 = Als;                            // 16 KB swizzled image
    float* c7 = (float*)((char*)Als + 16384);   // 32 KB fp32
    for (int rt = 0; rt < 4; ++rt) {
        f32x4 acc[5] = {};
        #pragma unroll
        for (int s = 0; s < 8; ++s) {
            int cch  = s * 4 + quad;                     // [0,32)
            int row  = 2 * (rt * 16 + l16) + (cch >> 4); // child row [0,128)
            int byte = (row * 256 + (cch & 15) * 16) ^ (((row >> 1) & 7) << 4);
            bfrag8 af = *(const bfrag8*)((const char*)h6 + byte);
            #pragma unroll
            for (int g = 0; g < 5; ++g)
                acc[g] = __builtin_amdgcn_mfma_f32_16x16x32_bf16(
                             af, Wfr[g][s], acc[g], 0, 0, 0);
        }
        #pragma unroll
        for (int rg = 0; rg < 4; ++rg) {
            int mloc = rt * 16 + quad * 4 + rg;          // [0,64)
            float gi  = acc[0][rg] + bi;
            float gfl = acc[1][rg] + bfl;
            float gfr = acc[2][rg] + bfr_;
            float go  = acc[3][rg] + bo;
            float gg  = acc[4][rg] + bg;
            float cl  = c6[(2 * mloc) * 128 + h];
            float cr  = c6[(2 * mloc + 1) * 128 + h];
            float cn  = sigf(gfl) * cl + sigf(gfr) * cr + sigf(gi) * tanh_f(gg);
            float hn  = sigf(go) * tanh_f(cn);
            c7[mloc * 128 + h] = cn;
            int byte = (mloc * 256 + h * 2) ^ (((mloc >> 1) & 7) << 4);
            *(short*)((char*)h7 + byte) = f2bf(hn);
        }
    }
    __syncthreads();   // h7/c7 complete

    // ---- lev8: 32 rows -> global (finish kernel consumes) ----
    for (int rt = 0; rt < 2; ++rt) {
        f32x4 acc[5] = {};
        #pragma unroll
        for (int s = 0; s < 8; ++s) {
            int cch  = s * 4 + quad;
            int row  = 2 * (rt * 16 + l16) + (cch >> 4); // child row [0,64)
            int byte = (row * 256 + (cch & 15) * 16) ^ (((row >> 1) & 7) << 4);
            bfrag8 af = *(const bfrag8*)((const char*)h7 + byte);
            #pragma unroll
            for (int g = 0; g < 5; ++g)
                acc[g] = __builtin_amdgcn_mfma_f32_16x16x32_bf16(
                             af, Wfr[g][s], acc[g], 0, 0, 0);
        }
        #pragma unroll
        for (int rg = 0; rg < 4; ++rg) {
            int mloc = rt * 16 + quad * 4 + rg;          // [0,32)
            int m    = b * 32 + mloc;                    // global lev8 row
            float gi  = acc[0][rg] + bi;
            float gfl = acc[1][rg] + bfl;
            float gfr = acc[2][rg] + bfr_;
            float go  = acc[3][rg] + bo;
            float gg  = acc[4][rg] + bg;
            float cl  = c7[(2 * mloc) * 128 + h];
            float cr  = c7[(2 * mloc + 1) * 128 + h];
            float cn  = sigf(gfl) * cl + sigf(gfr) * cr + sigf(gi) * tanh_f(gg);
            float hn  = sigf(go) * tanh_f(cn);
            hout[(((size_t)((m & 1) * 16 + (h >> 3))) * 64 + (m >> 1)) * 8
                 + (h & 7)] = f2bf(hn);
            cout_[(size_t)m * 128 + h] = cn;
        }
    }
}

// ---------------- single-block finisher: levels 9..12 ----------------
__global__ __launch_bounds__(512) void finish_kernel(
    const short* __restrict__ hin,   // [32][64] units (128-row chunk layout)
    const float* __restrict__ cin,   // [128][128] f32
    const short* __restrict__ Wch, const float* __restrict__ bias,
    float* __restrict__ out)         // [8][128]
{
    __shared__ short hP[32 * 64 * 8];   // 32 KB ping
    __shared__ short hQ[32 * 32 * 8];   // 16 KB pong
    __shared__ float cA[128 * 128];     // 64 KB
    __shared__ float cB[64 * 128];      // 32 KB
    const int tid  = threadIdx.x;
    const int w    = tid >> 6, lane = tid & 63;
    const int quad = lane >> 4, l16 = lane & 15;
    const int h    = w * 16 + l16;      // wave = h-group

    #pragma unroll
    for (int g = 0; g < 4; ++g)
        GLDS(hin + ((size_t)((g * 8 + w) * 64 + lane)) * 8,
             (char*)hP + ((g * 8 + w) * 64) * 16);
    #pragma unroll
    for (int g = 0; g < 8; ++g)
        GLDS(cin + ((size_t)((g * 8 + w) * 64 + lane)) * 4,
             (char*)cA + ((g * 8 + w) * 64) * 16);

    bfrag8 Wfr[5][8];
    #pragma unroll
    for (int g = 0; g < 5; ++g)
        #pragma unroll
        for (int s = 0; s < 8; ++s)
            Wfr[g][s] = *(const bfrag8*)(Wch + ((size_t)(s * 4 + quad) * 640
                                                + g * 128 + h) * 8);
    const float bi  = bias[h],       bfl = bias[128 + h], bfr_ = bias[256 + h];
    const float bo  = bias[384 + h], bg  = bias[512 + h];

    __syncthreads();

    #pragma unroll
    for (int t = 0; t < 4; ++t) {              // levels 9..12
        const int Mo = 64 >> t;                // 64, 32, 16, 8
        const short* hsrc = (t & 1) ? hQ : hP;
        short* hdst       = (t & 1) ? hP : hQ;
        const float* cread  = (t & 1) ? cB : cA;
        float*       cwrite = (t & 1) ? cA : cB;
        const int nrt = (Mo + 15) >> 4;

        for (int rt = 0; rt < nrt; ++rt) {
            f32x4 acc[5] = {};
            #pragma unroll
            for (int s = 0; s < 8; ++s) {
                bfrag8 af = *(const bfrag8*)(hsrc + ((s * 4 + quad) * Mo
                                                     + rt * 16 + l16) * 8);
                #pragma unroll
                for (int g = 0; g < 5; ++g)
                    acc[g] = __builtin_amdgcn_mfma_f32_16x16x32_bf16(
                                 af, Wfr[g][s], acc[g], 0, 0, 0);
            }
            #pragma unroll
            for (int rg = 0; rg < 4; ++rg) {
                int m = rt * 16 + quad * 4 + rg;
                if (m < Mo) {
                    float gi  = acc[0][rg] + bi;
                    float gfl = acc[1][rg] + bfl;
                    float gfr = acc[2][rg] + bfr_;
                    float go  = acc[3][rg] + bo;
                    float gg  = acc[4][rg] + bg;
                    float cl  = cread[(2 * m) * 128 + h];
                    float cr  = cread[(2 * m + 1) * 128 + h];
                    float cn  = sigf(gfl) * cl + sigf(gfr) * cr + sigf(gi) * tanh_f(gg);
                    float hn  = sigf(go) * tanh_f(cn);
                    if (t == 3) {
                        out[(size_t)m * 128 + h] = hn;
                    } else {
                        hdst[(((m & 1) * 16 + (h >> 3)) * (Mo >> 1) + (m >> 1)) * 8
                             + (h & 7)] = f2bf(hn);
                        cwrite[m * 128 + h] = cn;
                    }
                }
            }
        }
        __syncthreads();
    }
}

extern "C" void kernel_launch(void* const* d_in, const int* in_sizes, int n_in,
                              void* d_out, int out_size, void* d_ws, size_t ws_size,
                              hipStream_t stream)
{
    const float* x      = (const float*)d_in[0];
    const float* W_leaf = (const float*)d_in[1];
    const float* b_leaf = (const float*)d_in[2];
    const float* W_l    = (const float*)d_in[3];
    const float* W_r    = (const float*)d_in[4];
    const float* b      = (const float*)d_in[5];
    float* out = (float*)d_out;

    // workspace (~38.2 MB)
    char* p = (char*)d_ws;
    short* hA    = (short*)p; p += (size_t)32 * 16384 * 16 + 1024; //  8.4 MB
    short* hB    = (short*)p; p += (size_t)32 * 8192 * 16 + 1024;  //  4.2 MB
    float* c0    = (float*)p; p += (size_t)32768 * 128 * 4;        // 16.8 MB
    float* c1    = (float*)p; p += (size_t)16384 * 128 * 4;        //  8.4 MB
    short* WcatC = (short*)p; p += (size_t)32 * 640 * 16;          // 320 KB

    // 1) leaf (includes WcatC reorder fold + on-the-fly W_leaf conversion)
    leaf_kernel<<<dim3(256, 2), 256, 0, stream>>>(
        x, W_leaf, W_l, W_r, b_leaf, hA, c0, WcatC);

    // 2..6) levels 1..5, weight-stationary with nst amortization
    const short* hin = hA; const float* cin = c0;
    int M = 16384;
    for (int lev = 1; lev <= 5; ++lev) {
        short* ho = (lev & 1) ? hB : hA;
        float* co = (lev & 1) ? c1 : c0;
        int nst = (lev == 1) ? 4 : (lev == 2) ? 2 : (lev == 3) ? 2 : 1;
        level_ws_kernel<<<dim3(M / (64 * nst), 8), 256, 0, stream>>>(
            hin, cin, WcatC, b, ho, co, M, nst);
        hin = ho; cin = co;
        M >>= 1;
    }
    // after lev5: hin = hB ([32][512] units), cin = c1 ([1024][128])

    // 7) levels 6..8 fused: 4 blocks, outputs hA [32][64] + c0 [128][128]
    tail3_kernel<<<4, 512, 0, stream>>>(hB, c1, WcatC, b, hA, c0);

    // 8) levels 9..12: single-block finisher
    finish_kernel<<<1, 512, 0, stream>>>(hA, c0, WcatC, b, out);
}

// Round 10
// 167.437 us; speedup vs baseline: 1.1063x; 1.1063x over previous
//
#include <hip/hip_runtime.h>
#include <hip/hip_bf16.h>
#include <math.h>

// TreeLSTM, B=8, L=4096, D=300, H=128, 12 levels. Round 16:
// - R15 post-mortem: tail3 fusion regressed 16us (4-block parallelism
//   collapse; 3rd confirmation that fusing small levels loses to ~2.5us
//   dispatches). REVERTED to R14 structure (169.1us best).
// - New lever (traffic audit): R14 leaf grid (256,2) staged the SAME x rows
//   in both y-blocks -> x read twice (78 MB). Now ONE block computes all 256
//   output cols: acc[2][4][4] (128 VGPR), af fragments reused across both
//   n-halves, Bls widened to 8x256 units (32 KB). Grid (256,1). Saves ~39 MB
//   HBM (~6us).
// - Everything else R14-exact: level_ws + nst (4/2/1/1/1/1/1/1) for levels
//   1..8, single-block finish for 9..12, reorder folded into leaf.

typedef __attribute__((ext_vector_type(8))) short bfrag8;   // 8 bf16 = 4 VGPRs
typedef __attribute__((ext_vector_type(4))) float f32x4;

__device__ __forceinline__ float rcpf(float x) { return __builtin_amdgcn_rcpf(x); }
__device__ __forceinline__ float sigf(float x) { return rcpf(1.0f + __expf(-x)); }
__device__ __forceinline__ float tanh_f(float x) {
    float e = __expf(2.0f * x);              // x>>0: e=inf -> rcp=0 -> 1 ; x<<0: e=0 -> -1
    return 1.0f - 2.0f * rcpf(e + 1.0f);
}
__device__ __forceinline__ short f2bf(float f) {
    __hip_bfloat16 h = __float2bfloat16(&f == nullptr ? 0.0f : f);
    return *reinterpret_cast<short*>(&h);
}
__device__ __forceinline__ bfrag8 pack8(f32x4 a, f32x4 b) {
    union { int i[4]; bfrag8 v; } u;
    asm("v_cvt_pk_bf16_f32 %0, %1, %2" : "=v"(u.i[0]) : "v"(a[0]), "v"(a[1]));
    asm("v_cvt_pk_bf16_f32 %0, %1, %2" : "=v"(u.i[1]) : "v"(a[2]), "v"(a[3]));
    asm("v_cvt_pk_bf16_f32 %0, %1, %2" : "=v"(u.i[2]) : "v"(b[0]), "v"(b[1]));
    asm("v_cvt_pk_bf16_f32 %0, %1, %2" : "=v"(u.i[3]) : "v"(b[2]), "v"(b[3]));
    return u.v;
}
#define GLDS(gp, lp) __builtin_amdgcn_global_load_lds( \
    (const __attribute__((address_space(1))) void*)(gp), \
    (__attribute__((address_space(3))) void*)(lp), 16, 0, 0)

// ---------------- leaf: [32768,320fp32]@[320,256] + bias, split h/c ----------------
// One block per 128-row tile computes ALL 256 output cols (x staged once).
__global__ __launch_bounds__(256) void leaf_kernel(
    const float* __restrict__ x,     const float* __restrict__ Wleaf,
    const float* __restrict__ W_l,   const float* __restrict__ W_r,
    const float* __restrict__ bleaf,
    short* __restrict__ hD,       // level-1 A, chunk layout [32][16384] units
    float* __restrict__ cD,       // [32768][128] fp32
    short* __restrict__ Wcat_ch)  // [32][640] chunk units (for later levels)
{
    __shared__ float Als[128 * 64];     // 32 KB: [row][16 units], src-swizzled
    __shared__ short Bls[8 * 256 * 8];  // 32 KB: [c][n 0..256) units
    const int tid  = threadIdx.x;
    const int w    = tid >> 6, lane = tid & 63;
    const int quad = lane >> 4, l16 = lane & 15;
    const int mBlk = blockIdx.x * 128;
    const int waveM = (w >> 1) * 64, waveN = (w & 1) * 64;

    // ---- folded reorder: WcatC (163840 elems over 160 blocks x 1024) ----
    if (blockIdx.x < 160) {
        #pragma unroll
        for (int e = 0; e < 4; ++e) {
            int idx = blockIdx.x * 1024 + e * 256 + tid;
            int n = idx >> 8, k = idx & 255;
            float v = (k < 128) ? W_l[k * 640 + n] : W_r[(k - 128) * 640 + n];
            Wcat_ch[(((size_t)(k >> 3)) * 640 + n) * 8 + (k & 7)] = f2bf(v);
        }
    }

    f32x4 acc[2][4][4] = {};
    const f32x4 zero4 = {0.f, 0.f, 0.f, 0.f};

    for (int c = 0; c < 5; ++c) {           // K = 5 * 64 = 320 (300 + zero pad)
        const int k0c = c * 64;
        // ---- stage A (x) as fp32, XOR-swizzled source, linear LDS ----
        {
            const int q_lds = lane & 15;
            const int rsub  = lane >> 4;
            #pragma unroll
            for (int g = 0; g < 8; ++g) {
                int row = w * 32 + g * 4 + rsub;
                int q_g = (q_lds & 8) | ((q_lds & 7) ^ (row & 7));
                if (c < 4 || q_g < 11) {
                    GLDS(x + (size_t)(mBlk + row) * 300 + k0c + q_g * 4,
                         (char*)Als + (w * 32 + g * 4) * 256);
                } else {
                    *(f32x4*)((char*)Als + row * 256 + q_lds * 16) = zero4;  // pad k=300..319
                }
            }
        }
        // ---- stage B on the fly from W_leaf fp32 (2048 units, 8/thread) ----
        #pragma unroll
        for (int uu = 0; uu < 8; ++uu) {
            int ccl = uu, nl = tid;             // chunk-in-iter, col [0,256)
            int k0  = (c * 8 + ccl) * 8;
            f32x4 v0, v1;
            #pragma unroll
            for (int jj = 0; jj < 4; ++jj)
                v0[jj] = (k0 + jj < 300) ? Wleaf[(size_t)(k0 + jj) * 256 + nl] : 0.0f;
            #pragma unroll
            for (int jj = 0; jj < 4; ++jj)
                v1[jj] = (k0 + 4 + jj < 300) ? Wleaf[(size_t)(k0 + 4 + jj) * 256 + nl] : 0.0f;
            *(bfrag8*)(Bls + (ccl * 256 + nl) * 8) = pack8(v0, v1);
        }
        __syncthreads();
        #pragma unroll
        for (int ks = 0; ks < 2; ++ks) {
            const int ca = ks * 4 + quad;
            bfrag8 af[4];
            #pragma unroll
            for (int i = 0; i < 4; ++i) {
                int r  = waveM + i * 16 + l16;
                int u0 = 2 * ca, u1 = 2 * ca + 1;
                int s0 = (u0 & 8) | ((u0 & 7) ^ (r & 7));
                int s1 = (u1 & 8) | ((u1 & 7) ^ (r & 7));
                f32x4 a0 = *(const f32x4*)(Als + r * 64 + s0 * 4);
                f32x4 a1 = *(const f32x4*)(Als + r * 64 + s1 * 4);
                af[i] = pack8(a0, a1);
            }
            #pragma unroll
            for (int nh = 0; nh < 2; ++nh) {
                bfrag8 bf4[4];
                #pragma unroll
                for (int jn = 0; jn < 4; ++jn)
                    bf4[jn] = *(const bfrag8*)(Bls + (ca * 256 + nh * 128
                                                      + waveN + jn * 16 + l16) * 8);
                #pragma unroll
                for (int i = 0; i < 4; ++i)
                    #pragma unroll
                    for (int jn = 0; jn < 4; ++jn)
                        acc[nh][i][jn] = __builtin_amdgcn_mfma_f32_16x16x32_bf16(
                                             af[i], bf4[jn], acc[nh][i][jn], 0, 0, 0);
            }
        }
        __syncthreads();
    }

    #pragma unroll
    for (int nh = 0; nh < 2; ++nh) {
        #pragma unroll
        for (int i = 0; i < 4; ++i) {
            int row0 = mBlk + waveM + i * 16 + quad * 4;
            #pragma unroll
            for (int jn = 0; jn < 4; ++jn) {
                int col = nh * 128 + waveN + jn * 16 + l16;
                float bv = bleaf[col];
                #pragma unroll
                for (int rg = 0; rg < 4; ++rg) {
                    float v = acc[nh][i][jn][rg] + bv;
                    int m = row0 + rg;
                    if (nh == 0) {
                        int hc = col;
                        hD[(((size_t)((m & 1) * 16 + (hc >> 3))) * 16384 + (m >> 1)) * 8
                           + (hc & 7)] = f2bf(v);
                    } else {
                        cD[(size_t)m * 128 + (col - 128)] = v;
                    }
                }
            }
        }
    }
}

// ---------------- weight-stationary level kernel (levels 1..8) ----------------
// PROVEN SHAPE: Wfr loaded ONCE at kernel scope. nst row-subtiles amortize.
__global__ __launch_bounds__(256, 2) void level_ws_kernel(
    const short* __restrict__ A,      // [32][M] chunk units
    const float* __restrict__ cprev,  // [2M][128] fp32
    const short* __restrict__ Wch,    // [32][640] chunk units
    const float* __restrict__ bias,   // [640]
    short* __restrict__ hout, float* __restrict__ cout_,
    int M, int nst)
{
    __shared__ short Als[32 * 64 * 8];   // 32 KB, [c][row]
    const int tid  = threadIdx.x;
    const int w    = tid >> 6, lane = tid & 63;
    const int quad = lane >> 4, l16 = lane & 15;
    const int j   = blockIdx.y;
    const int tb0 = blockIdx.x * 64 * nst;
    const int h   = j * 16 + l16;

    // stage subtile 0 (overlaps the Wfr loads below)
    #pragma unroll
    for (int s = 0; s < 8; ++s)
        GLDS(A + ((size_t)(s * 4 + w) * M + tb0 + lane) * 8,
             (char*)Als + (s * 4 + w) * 1024);

    bfrag8 Wfr[5][8];
    #pragma unroll
    for (int g = 0; g < 5; ++g)
        #pragma unroll
        for (int s = 0; s < 8; ++s)
            Wfr[g][s] = *(const bfrag8*)(Wch + ((size_t)(s * 4 + quad) * 640
                                                + g * 128 + h) * 8);
    const float bi  = bias[h],       bfl = bias[128 + h], bfr_ = bias[256 + h];
    const float bo  = bias[384 + h], bg  = bias[512 + h];

    const int Mn = M >> 1;
    for (int st = 0; st < nst; ++st) {
        const int tb = tb0 + st * 64;
        __syncthreads();                 // staging of subtile st complete

        f32x4 acc[5] = {};
        #pragma unroll
        for (int s = 0; s < 8; ++s) {
            bfrag8 af = *(const bfrag8*)(Als + ((s * 4 + quad) * 64 + w * 16 + l16) * 8);
            #pragma unroll
            for (int g = 0; g < 5; ++g)
                acc[g] = __builtin_amdgcn_mfma_f32_16x16x32_bf16(af, Wfr[g][s], acc[g], 0, 0, 0);
        }

        if (st + 1 < nst) {
            __syncthreads();             // all Als reads done; restage
            #pragma unroll
            for (int s = 0; s < 8; ++s)
                GLDS(A + ((size_t)(s * 4 + w) * M + tb + 64 + lane) * 8,
                     (char*)Als + (s * 4 + w) * 1024);
        }

        #pragma unroll
        for (int rg = 0; rg < 4; ++rg) {
            int m = tb + w * 16 + quad * 4 + rg;
            float gi  = acc[0][rg] + bi;
            float gfl = acc[1][rg] + bfl;
            float gfr = acc[2][rg] + bfr_;
            float go  = acc[3][rg] + bo;
            float gg  = acc[4][rg] + bg;
            float cl  = cprev[(size_t)(2 * m) * 128 + h];
            float cr  = cprev[(size_t)(2 * m + 1) * 128 + h];
            float cn  = sigf(gfl) * cl + sigf(gfr) * cr + sigf(gi) * tanh_f(gg);
            float hn  = sigf(go) * tanh_f(cn);
            hout[(((size_t)((m & 1) * 16 + (h >> 3))) * Mn + (m >> 1)) * 8
                 + (h & 7)] = f2bf(hn);
            cout_[(size_t)m * 128 + h] = cn;
        }
    }
}

// ---------------- single-block finisher: levels 9..12 ----------------
__global__ __launch_bounds__(512) void finish_kernel(
    const short* __restrict__ hin,   // [32][64] units (128-row chunk layout)
    const float* __restrict__ cin,   // [128][128] f32
    const short* __restrict__ Wch, const float* __restrict__ bias,
    float* __restrict__ out)         // [8][128]
{
    __shared__ short hP[32 * 64 * 8];   // 32 KB ping
    __shared__ short hQ[32 * 32 * 8];   // 16 KB pong
    __shared__ float cA[128 * 128];     // 64 KB
    __shared__ float cB[64 * 128];      // 32 KB
    const int tid  = threadIdx.x;
    const int w    = tid >> 6, lane = tid & 63;
    const int quad = lane >> 4, l16 = lane & 15;
    const int h    = w * 16 + l16;      // wave = h-group

    #pragma unroll
    for (int g = 0; g < 4; ++g)
        GLDS(hin + ((size_t)((g * 8 + w) * 64 + lane)) * 8,
             (char*)hP + ((g * 8 + w) * 64) * 16);
    #pragma unroll
    for (int g = 0; g < 8; ++g)
        GLDS(cin + ((size_t)((g * 8 + w) * 64 + lane)) * 4,
             (char*)cA + ((g * 8 + w) * 64) * 16);

    bfrag8 Wfr[5][8];
    #pragma unroll
    for (int g = 0; g < 5; ++g)
        #pragma unroll
        for (int s = 0; s < 8; ++s)
            Wfr[g][s] = *(const bfrag8*)(Wch + ((size_t)(s * 4 + quad) * 640
                                                + g * 128 + h) * 8);
    const float bi  = bias[h],       bfl = bias[128 + h], bfr_ = bias[256 + h];
    const float bo  = bias[384 + h], bg  = bias[512 + h];

    __syncthreads();

    #pragma unroll
    for (int t = 0; t < 4; ++t) {              // levels 9..12
        const int Mo = 64 >> t;                // 64, 32, 16, 8
        const short* hsrc = (t & 1) ? hQ : hP;
        short* hdst       = (t & 1) ? hP : hQ;
        const float* cread  = (t & 1) ? cB : cA;
        float*       cwrite = (t & 1) ? cA : cB;
        const int nrt = (Mo + 15) >> 4;

        for (int rt = 0; rt < nrt; ++rt) {
            f32x4 acc[5] = {};
            #pragma unroll
            for (int s = 0; s < 8; ++s) {
                bfrag8 af = *(const bfrag8*)(hsrc + ((s * 4 + quad) * Mo
                                                     + rt * 16 + l16) * 8);
                #pragma unroll
                for (int g = 0; g < 5; ++g)
                    acc[g] = __builtin_amdgcn_mfma_f32_16x16x32_bf16(
                                 af, Wfr[g][s], acc[g], 0, 0, 0);
            }
            #pragma unroll
            for (int rg = 0; rg < 4; ++rg) {
                int m = rt * 16 + quad * 4 + rg;
                if (m < Mo) {
                    float gi  = acc[0][rg] + bi;
                    float gfl = acc[1][rg] + bfl;
                    float gfr = acc[2][rg] + bfr_;
                    float go  = acc[3][rg] + bo;
                    float gg  = acc[4][rg] + bg;
                    float cl  = cread[(2 * m) * 128 + h];
                    float cr  = cread[(2 * m + 1) * 128 + h];
                    float cn  = sigf(gfl) * cl + sigf(gfr) * cr + sigf(gi) * tanh_f(gg);
                    float hn  = sigf(go) * tanh_f(cn);
                    if (t == 3) {
                        out[(size_t)m * 128 + h] = hn;
                    } else {
                        hdst[(((m & 1) * 16 + (h >> 3)) * (Mo >> 1) + (m >> 1)) * 8
                             + (h & 7)] = f2bf(hn);
                        cwrite[m * 128 + h] = cn;
                    }
                }
            }
        }
        __syncthreads();
    }
}

extern "C" void kernel_launch(void* const* d_in, const int* in_sizes, int n_in,
                              void* d_out, int out_size, void* d_ws, size_t ws_size,
                              hipStream_t stream)
{
    const float* x      = (const float*)d_in[0];
    const float* W_leaf = (const float*)d_in[1];
    const float* b_leaf = (const float*)d_in[2];
    const float* W_l    = (const float*)d_in[3];
    const float* W_r    = (const float*)d_in[4];
    const float* b      = (const float*)d_in[5];
    float* out = (float*)d_out;

    // workspace (~38.2 MB)
    char* p = (char*)d_ws;
    short* hA    = (short*)p; p += (size_t)32 * 16384 * 16 + 1024; //  8.4 MB
    short* hB    = (short*)p; p += (size_t)32 * 8192 * 16 + 1024;  //  4.2 MB
    float* c0    = (float*)p; p += (size_t)32768 * 128 * 4;        // 16.8 MB
    float* c1    = (float*)p; p += (size_t)16384 * 128 * 4;        //  8.4 MB
    short* WcatC = (short*)p; p += (size_t)32 * 640 * 16;          // 320 KB

    // 1) leaf (reorder fold + on-the-fly W_leaf conversion; x staged ONCE)
    leaf_kernel<<<256, 256, 0, stream>>>(
        x, W_leaf, W_l, W_r, b_leaf, hA, c0, WcatC);

    // 2..9) levels 1..8, weight-stationary with nst amortization (R14 config)
    const short* hin = hA; const float* cin = c0;
    int M = 16384;
    for (int lev = 1; lev <= 8; ++lev) {
        short* ho = (lev & 1) ? hB : hA;
        float* co = (lev & 1) ? c1 : c0;
        int nst = (lev == 1) ? 4 : (lev == 2) ? 2 : 1;
        level_ws_kernel<<<dim3(M / (64 * nst), 8), 256, 0, stream>>>(
            hin, cin, WcatC, b, ho, co, M, nst);
        hin = ho; cin = co;
        M >>= 1;
    }

    // 10) levels 9..12: single-block finisher (hA [32][64], c0 [128][128])
    finish_kernel<<<1, 512, 0, stream>>>(hA, c0, WcatC, b, out);
}

// Round 11
// 167.311 us; speedup vs baseline: 1.1071x; 1.0008x over previous
//
#include <hip/hip_runtime.h>
#include <hip/hip_bf16.h>
#include <math.h>

// TreeLSTM, B=8, L=4096, D=300, H=128, 12 levels. Round 17:
// - R16 post-mortem: x-dedup saved 1.7us not 6 (L3 absorbed the re-read).
//   Lesson: only HBM WRITES + cold reads pay full price.
// - This round: (a) bf16 COLUMN-BLOCKED c (layout c[j][m][16], j=h>>4) for
//   the two largest c hops only (leaf->lev1, lev1->lev2). Col-blocking is
//   required because row-major bf16 c halves line utilization (64B line
//   spans two j-blocks); col-blocked keeps each block's slice contiguous.
//   2 quantization points, >=10 levels from root -> error attenuates ~0.71^n.
//   (b) lev3 nst=2 (256 blocks, still full GPU). (c) f2bf cleanup.
// - Proven structure unchanged: leaf(+reorder fold) -> 8x level_ws(nst) ->
//   single-block finish. Laws: Wfr loaded once at kernel scope, (256,2);
//   no cross-block fusion of small levels.

typedef __attribute__((ext_vector_type(8))) short bfrag8;   // 8 bf16 = 4 VGPRs
typedef __attribute__((ext_vector_type(4))) float f32x4;

__device__ __forceinline__ float rcpf(float x) { return __builtin_amdgcn_rcpf(x); }
__device__ __forceinline__ float sigf(float x) { return rcpf(1.0f + __expf(-x)); }
__device__ __forceinline__ float tanh_f(float x) {
    float e = __expf(2.0f * x);              // x>>0: e=inf -> rcp=0 -> 1 ; x<<0: e=0 -> -1
    return 1.0f - 2.0f * rcpf(e + 1.0f);
}
__device__ __forceinline__ short f2bf(float f) {
    __hip_bfloat16 h = __float2bfloat16(f);
    return *reinterpret_cast<short*>(&h);
}
__device__ __forceinline__ float bf2f(short s) {
    union { unsigned int u; float f; } v;
    v.u = ((unsigned int)(unsigned short)s) << 16;
    return v.f;
}
__device__ __forceinline__ bfrag8 pack8(f32x4 a, f32x4 b) {
    union { int i[4]; bfrag8 v; } u;
    asm("v_cvt_pk_bf16_f32 %0, %1, %2" : "=v"(u.i[0]) : "v"(a[0]), "v"(a[1]));
    asm("v_cvt_pk_bf16_f32 %0, %1, %2" : "=v"(u.i[1]) : "v"(a[2]), "v"(a[3]));
    asm("v_cvt_pk_bf16_f32 %0, %1, %2" : "=v"(u.i[2]) : "v"(b[0]), "v"(b[1]));
    asm("v_cvt_pk_bf16_f32 %0, %1, %2" : "=v"(u.i[3]) : "v"(b[2]), "v"(b[3]));
    return u.v;
}
#define GLDS(gp, lp) __builtin_amdgcn_global_load_lds( \
    (const __attribute__((address_space(1))) void*)(gp), \
    (__attribute__((address_space(3))) void*)(lp), 16, 0, 0)

// ---------------- leaf: [32768,320fp32]@[320,256] + bias, split h/c ----------------
// One block per 128-row tile computes ALL 256 output cols (x staged once).
// c output: bf16 COLUMN-BLOCKED  c[j][m][16], j = h>>4  (32768 rows).
__global__ __launch_bounds__(256) void leaf_kernel(
    const float* __restrict__ x,     const float* __restrict__ Wleaf,
    const float* __restrict__ W_l,   const float* __restrict__ W_r,
    const float* __restrict__ bleaf,
    short* __restrict__ hD,       // level-1 A, chunk layout [32][16384] units
    short* __restrict__ cDb,      // bf16 col-blocked [8][32768][16]
    short* __restrict__ Wcat_ch)  // [32][640] chunk units (for later levels)
{
    __shared__ float Als[128 * 64];     // 32 KB: [row][16 units], src-swizzled
    __shared__ short Bls[8 * 256 * 8];  // 32 KB: [c][n 0..256) units
    const int tid  = threadIdx.x;
    const int w    = tid >> 6, lane = tid & 63;
    const int quad = lane >> 4, l16 = lane & 15;
    const int mBlk = blockIdx.x * 128;
    const int waveM = (w >> 1) * 64, waveN = (w & 1) * 64;

    // ---- folded reorder: WcatC (163840 elems over 160 blocks x 1024) ----
    if (blockIdx.x < 160) {
        #pragma unroll
        for (int e = 0; e < 4; ++e) {
            int idx = blockIdx.x * 1024 + e * 256 + tid;
            int n = idx >> 8, k = idx & 255;
            float v = (k < 128) ? W_l[k * 640 + n] : W_r[(k - 128) * 640 + n];
            Wcat_ch[(((size_t)(k >> 3)) * 640 + n) * 8 + (k & 7)] = f2bf(v);
        }
    }

    f32x4 acc[2][4][4] = {};
    const f32x4 zero4 = {0.f, 0.f, 0.f, 0.f};

    for (int c = 0; c < 5; ++c) {           // K = 5 * 64 = 320 (300 + zero pad)
        const int k0c = c * 64;
        // ---- stage A (x) as fp32, XOR-swizzled source, linear LDS ----
        {
            const int q_lds = lane & 15;
            const int rsub  = lane >> 4;
            #pragma unroll
            for (int g = 0; g < 8; ++g) {
                int row = w * 32 + g * 4 + rsub;
                int q_g = (q_lds & 8) | ((q_lds & 7) ^ (row & 7));
                if (c < 4 || q_g < 11) {
                    GLDS(x + (size_t)(mBlk + row) * 300 + k0c + q_g * 4,
                         (char*)Als + (w * 32 + g * 4) * 256);
                } else {
                    *(f32x4*)((char*)Als + row * 256 + q_lds * 16) = zero4;  // pad k=300..319
                }
            }
        }
        // ---- stage B on the fly from W_leaf fp32 (2048 units, 8/thread) ----
        #pragma unroll
        for (int uu = 0; uu < 8; ++uu) {
            int ccl = uu, nl = tid;             // chunk-in-iter, col [0,256)
            int k0  = (c * 8 + ccl) * 8;
            f32x4 v0, v1;
            #pragma unroll
            for (int jj = 0; jj < 4; ++jj)
                v0[jj] = (k0 + jj < 300) ? Wleaf[(size_t)(k0 + jj) * 256 + nl] : 0.0f;
            #pragma unroll
            for (int jj = 0; jj < 4; ++jj)
                v1[jj] = (k0 + 4 + jj < 300) ? Wleaf[(size_t)(k0 + 4 + jj) * 256 + nl] : 0.0f;
            *(bfrag8*)(Bls + (ccl * 256 + nl) * 8) = pack8(v0, v1);
        }
        __syncthreads();
        #pragma unroll
        for (int ks = 0; ks < 2; ++ks) {
            const int ca = ks * 4 + quad;
            bfrag8 af[4];
            #pragma unroll
            for (int i = 0; i < 4; ++i) {
                int r  = waveM + i * 16 + l16;
                int u0 = 2 * ca, u1 = 2 * ca + 1;
                int s0 = (u0 & 8) | ((u0 & 7) ^ (r & 7));
                int s1 = (u1 & 8) | ((u1 & 7) ^ (r & 7));
                f32x4 a0 = *(const f32x4*)(Als + r * 64 + s0 * 4);
                f32x4 a1 = *(const f32x4*)(Als + r * 64 + s1 * 4);
                af[i] = pack8(a0, a1);
            }
            #pragma unroll
            for (int nh = 0; nh < 2; ++nh) {
                bfrag8 bf4[4];
                #pragma unroll
                for (int jn = 0; jn < 4; ++jn)
                    bf4[jn] = *(const bfrag8*)(Bls + (ca * 256 + nh * 128
                                                      + waveN + jn * 16 + l16) * 8);
                #pragma unroll
                for (int i = 0; i < 4; ++i)
                    #pragma unroll
                    for (int jn = 0; jn < 4; ++jn)
                        acc[nh][i][jn] = __builtin_amdgcn_mfma_f32_16x16x32_bf16(
                                             af[i], bf4[jn], acc[nh][i][jn], 0, 0, 0);
            }
        }
        __syncthreads();
    }

    #pragma unroll
    for (int nh = 0; nh < 2; ++nh) {
        #pragma unroll
        for (int i = 0; i < 4; ++i) {
            int row0 = mBlk + waveM + i * 16 + quad * 4;
            #pragma unroll
            for (int jn = 0; jn < 4; ++jn) {
                int col = nh * 128 + waveN + jn * 16 + l16;
                float bv = bleaf[col];
                #pragma unroll
                for (int rg = 0; rg < 4; ++rg) {
                    float v = acc[nh][i][jn][rg] + bv;
                    int m = row0 + rg;
                    if (nh == 0) {
                        int hc = col;
                        hD[(((size_t)((m & 1) * 16 + (hc >> 3))) * 16384 + (m >> 1)) * 8
                           + (hc & 7)] = f2bf(v);
                    } else {
                        int ch = col - 128;
                        cDb[(size_t)(ch >> 4) * 32768 * 16 + (size_t)m * 16 + (ch & 15)]
                            = f2bf(v);
                    }
                }
            }
        }
    }
}

// ---------------- weight-stationary level kernel (levels 1..8) ----------------
// PROVEN SHAPE: Wfr loaded ONCE at kernel scope. nst row-subtiles amortize.
// CIN_BF / COUT_BF select bf16 col-blocked c[j][rows][16] vs fp32 [rows][128].
template<int CIN_BF, int COUT_BF>
__global__ __launch_bounds__(256, 2) void level_ws_t(
    const short* __restrict__ A,      // [32][M] chunk units
    const void*  __restrict__ cprev,  // 2M rows
    const short* __restrict__ Wch,    // [32][640] chunk units
    const float* __restrict__ bias,   // [640]
    short* __restrict__ hout, void* __restrict__ cout_,  // M rows
    int M, int nst)
{
    __shared__ short Als[32 * 64 * 8];   // 32 KB, [c][row]
    const int tid  = threadIdx.x;
    const int w    = tid >> 6, lane = tid & 63;
    const int quad = lane >> 4, l16 = lane & 15;
    const int j   = blockIdx.y;
    const int tb0 = blockIdx.x * 64 * nst;
    const int h   = j * 16 + l16;

    // stage subtile 0 (overlaps the Wfr loads below)
    #pragma unroll
    for (int s = 0; s < 8; ++s)
        GLDS(A + ((size_t)(s * 4 + w) * M + tb0 + lane) * 8,
             (char*)Als + (s * 4 + w) * 1024);

    bfrag8 Wfr[5][8];
    #pragma unroll
    for (int g = 0; g < 5; ++g)
        #pragma unroll
        for (int s = 0; s < 8; ++s)
            Wfr[g][s] = *(const bfrag8*)(Wch + ((size_t)(s * 4 + quad) * 640
                                                + g * 128 + h) * 8);
    const float bi  = bias[h],       bfl = bias[128 + h], bfr_ = bias[256 + h];
    const float bo  = bias[384 + h], bg  = bias[512 + h];

    const int Mn = M >> 1;
    for (int st = 0; st < nst; ++st) {
        const int tb = tb0 + st * 64;
        __syncthreads();                 // staging of subtile st complete

        f32x4 acc[5] = {};
        #pragma unroll
        for (int s = 0; s < 8; ++s) {
            bfrag8 af = *(const bfrag8*)(Als + ((s * 4 + quad) * 64 + w * 16 + l16) * 8);
            #pragma unroll
            for (int g = 0; g < 5; ++g)
                acc[g] = __builtin_amdgcn_mfma_f32_16x16x32_bf16(af, Wfr[g][s], acc[g], 0, 0, 0);
        }

        if (st + 1 < nst) {
            __syncthreads();             // all Als reads done; restage
            #pragma unroll
            for (int s = 0; s < 8; ++s)
                GLDS(A + ((size_t)(s * 4 + w) * M + tb + 64 + lane) * 8,
                     (char*)Als + (s * 4 + w) * 1024);
        }

        #pragma unroll
        for (int rg = 0; rg < 4; ++rg) {
            int m = tb + w * 16 + quad * 4 + rg;
            float gi  = acc[0][rg] + bi;
            float gfl = acc[1][rg] + bfl;
            float gfr = acc[2][rg] + bfr_;
            float go  = acc[3][rg] + bo;
            float gg  = acc[4][rg] + bg;
            float cl, cr;
            if (CIN_BF) {
                const short* cp = (const short*)cprev;
                size_t base = (size_t)(h >> 4) * ((size_t)2 * M) * 16
                              + (size_t)(2 * m) * 16 + (h & 15);
                cl = bf2f(cp[base]);
                cr = bf2f(cp[base + 16]);
            } else {
                const float* cp = (const float*)cprev;
                cl = cp[(size_t)(2 * m) * 128 + h];
                cr = cp[(size_t)(2 * m + 1) * 128 + h];
            }
            float cn  = sigf(gfl) * cl + sigf(gfr) * cr + sigf(gi) * tanh_f(gg);
            float hn  = sigf(go) * tanh_f(cn);
            hout[(((size_t)((m & 1) * 16 + (h >> 3))) * Mn + (m >> 1)) * 8
                 + (h & 7)] = f2bf(hn);
            if (COUT_BF) {
                ((short*)cout_)[(size_t)(h >> 4) * (size_t)M * 16
                                + (size_t)m * 16 + (h & 15)] = f2bf(cn);
            } else {
                ((float*)cout_)[(size_t)m * 128 + h] = cn;
            }
        }
    }
}

// ---------------- single-block finisher: levels 9..12 ----------------
__global__ __launch_bounds__(512) void finish_kernel(
    const short* __restrict__ hin,   // [32][64] units (128-row chunk layout)
    const float* __restrict__ cin,   // [128][128] f32
    const short* __restrict__ Wch, const float* __restrict__ bias,
    float* __restrict__ out)         // [8][128]
{
    __shared__ short hP[32 * 64 * 8];   // 32 KB ping
    __shared__ short hQ[32 * 32 * 8];   // 16 KB pong
    __shared__ float cA[128 * 128];     // 64 KB
    __shared__ float cB[64 * 128];      // 32 KB
    const int tid  = threadIdx.x;
    const int w    = tid >> 6, lane = tid & 63;
    const int quad = lane >> 4, l16 = lane & 15;
    const int h    = w * 16 + l16;      // wave = h-group

    #pragma unroll
    for (int g = 0; g < 4; ++g)
        GLDS(hin + ((size_t)((g * 8 + w) * 64 + lane)) * 8,
             (char*)hP + ((g * 8 + w) * 64) * 16);
    #pragma unroll
    for (int g = 0; g < 8; ++g)
        GLDS(cin + ((size_t)((g * 8 + w) * 64 + lane)) * 4,
             (char*)cA + ((g * 8 + w) * 64) * 16);

    bfrag8 Wfr[5][8];
    #pragma unroll
    for (int g = 0; g < 5; ++g)
        #pragma unroll
        for (int s = 0; s < 8; ++s)
            Wfr[g][s] = *(const bfrag8*)(Wch + ((size_t)(s * 4 + quad) * 640
                                                + g * 128 + h) * 8);
    const float bi  = bias[h],       bfl = bias[128 + h], bfr_ = bias[256 + h];
    const float bo  = bias[384 + h], bg  = bias[512 + h];

    __syncthreads();

    #pragma unroll
    for (int t = 0; t < 4; ++t) {              // levels 9..12
        const int Mo = 64 >> t;                // 64, 32, 16, 8
        const short* hsrc = (t & 1) ? hQ : hP;
        short* hdst       = (t & 1) ? hP : hQ;
        const float* cread  = (t & 1) ? cB : cA;
        float*       cwrite = (t & 1) ? cA : cB;
        const int nrt = (Mo + 15) >> 4;

        for (int rt = 0; rt < nrt; ++rt) {
            f32x4 acc[5] = {};
            #pragma unroll
            for (int s = 0; s < 8; ++s) {
                bfrag8 af = *(const bfrag8*)(hsrc + ((s * 4 + quad) * Mo
                                                     + rt * 16 + l16) * 8);
                #pragma unroll
                for (int g = 0; g < 5; ++g)
                    acc[g] = __builtin_amdgcn_mfma_f32_16x16x32_bf16(
                                 af, Wfr[g][s], acc[g], 0, 0, 0);
            }
            #pragma unroll
            for (int rg = 0; rg < 4; ++rg) {
                int m = rt * 16 + quad * 4 + rg;
                if (m < Mo) {
                    float gi  = acc[0][rg] + bi;
                    float gfl = acc[1][rg] + bfl;
                    float gfr = acc[2][rg] + bfr_;
                    float go  = acc[3][rg] + bo;
                    float gg  = acc[4][rg] + bg;
                    float cl  = cread[(2 * m) * 128 + h];
                    float cr  = cread[(2 * m + 1) * 128 + h];
                    float cn  = sigf(gfl) * cl + sigf(gfr) * cr + sigf(gi) * tanh_f(gg);
                    float hn  = sigf(go) * tanh_f(cn);
                    if (t == 3) {
                        out[(size_t)m * 128 + h] = hn;
                    } else {
                        hdst[(((m & 1) * 16 + (h >> 3)) * (Mo >> 1) + (m >> 1)) * 8
                             + (h & 7)] = f2bf(hn);
                        cwrite[m * 128 + h] = cn;
                    }
                }
            }
        }
        __syncthreads();
    }
}

extern "C" void kernel_launch(void* const* d_in, const int* in_sizes, int n_in,
                              void* d_out, int out_size, void* d_ws, size_t ws_size,
                              hipStream_t stream)
{
    const float* x      = (const float*)d_in[0];
    const float* W_leaf = (const float*)d_in[1];
    const float* b_leaf = (const float*)d_in[2];
    const float* W_l    = (const float*)d_in[3];
    const float* W_r    = (const float*)d_in[4];
    const float* b      = (const float*)d_in[5];
    float* out = (float*)d_out;

    // workspace (~38.2 MB; c0/c1 sized for their largest (fp32) use)
    char* p = (char*)d_ws;
    short* hA    = (short*)p; p += (size_t)32 * 16384 * 16 + 1024; //  8.4 MB
    short* hB    = (short*)p; p += (size_t)32 * 8192 * 16 + 1024;  //  4.2 MB
    char*  c0    = p;         p += (size_t)32768 * 128 * 4;        // 16.8 MB
    char*  c1    = p;         p += (size_t)16384 * 128 * 4;        //  8.4 MB
    short* WcatC = (short*)p; p += (size_t)32 * 640 * 16;          // 320 KB

    // 1) leaf: h -> hA, c -> c0 as bf16 col-blocked [8][32768][16]
    leaf_kernel<<<256, 256, 0, stream>>>(
        x, W_leaf, W_l, W_r, b_leaf, hA, (short*)c0, WcatC);

    // 2) lev1: cin bf16 (c0), cout bf16 col-blocked (c1); M=16384, nst=4
    level_ws_t<1, 1><<<dim3(16384 / 256, 8), 256, 0, stream>>>(
        hA, c0, WcatC, b, hB, c1, 16384, 4);
    // 3) lev2: cin bf16 (c1), cout fp32 (c0); M=8192, nst=2
    level_ws_t<1, 0><<<dim3(8192 / 128, 8), 256, 0, stream>>>(
        hB, c1, WcatC, b, hA, c0, 8192, 2);

    // 4..9) levels 3..8 fp32 c; lev3 nst=2, rest nst=1
    const short* hin = hA; const char* cin = c0;
    int M = 4096;
    for (int lev = 3; lev <= 8; ++lev) {
        short* ho = (lev & 1) ? hB : hA;
        char*  co = (lev & 1) ? c1 : c0;
        int nst = (lev == 3) ? 2 : 1;
        level_ws_t<0, 0><<<dim3(M / (64 * nst), 8), 256, 0, stream>>>(
            hin, cin, WcatC, b, ho, co, M, nst);
        hin = ho; cin = co;
        M >>= 1;
    }
    // after lev8: hin = hA ([32][64] units), cin = c0 ([128][128] fp32)

    // 10) levels 9..12: single-block finisher
    finish_kernel<<<1, 512, 0, stream>>>(hA, (const float*)c0, WcatC, b, out);
}

// Round 12
// 166.230 us; speedup vs baseline: 1.1143x; 1.0065x over previous
//
#include <hip/hip_runtime.h>
#include <hip/hip_bf16.h>
#include <math.h>

// TreeLSTM, B=8, L=4096, D=300, H=128, 12 levels. Round 18:
// - R17 exposed leaf = 45us, occ 9.7%: R16's n-merge left 256 blocks
//   (1/CU) and 64 serial scalar W_leaf loads/thread/iter. Fix:
//   (a) reorder dispatch restored (WcatC + bf16 WlfC, ~2us) -> B staged
//       via 8 GLDS/wave + b128 fragment reads (R9-proven layout);
//   (b) 64-row blocks -> 512 blocks = 2 blocks/CU (LDS 48 KB, acc[4][4]);
//       wave w owns col-quarter. x still read exactly once.
// - Kept from R17: bf16 col-blocked c for leaf->lev1->lev2 hops (absmax
//   unchanged), level_ws_t nst (4/2/2/1...), single-block finish.
// - Laws: Wfr once at kernel scope, (256,2); no cross-block small-level
//   fusion; only HBM writes + cold reads pay full price.

typedef __attribute__((ext_vector_type(8))) short bfrag8;   // 8 bf16 = 4 VGPRs
typedef __attribute__((ext_vector_type(4))) float f32x4;

__device__ __forceinline__ float rcpf(float x) { return __builtin_amdgcn_rcpf(x); }
__device__ __forceinline__ float sigf(float x) { return rcpf(1.0f + __expf(-x)); }
__device__ __forceinline__ float tanh_f(float x) {
    float e = __expf(2.0f * x);              // x>>0: e=inf -> rcp=0 -> 1 ; x<<0: e=0 -> -1
    return 1.0f - 2.0f * rcpf(e + 1.0f);
}
__device__ __forceinline__ short f2bf(float f) {
    __hip_bfloat16 h = __float2bfloat16(f);
    return *reinterpret_cast<short*>(&h);
}
__device__ __forceinline__ float bf2f(short s) {
    union { unsigned int u; float f; } v;
    v.u = ((unsigned int)(unsigned short)s) << 16;
    return v.f;
}
__device__ __forceinline__ bfrag8 pack8(f32x4 a, f32x4 b) {
    union { int i[4]; bfrag8 v; } u;
    asm("v_cvt_pk_bf16_f32 %0, %1, %2" : "=v"(u.i[0]) : "v"(a[0]), "v"(a[1]));
    asm("v_cvt_pk_bf16_f32 %0, %1, %2" : "=v"(u.i[1]) : "v"(a[2]), "v"(a[3]));
    asm("v_cvt_pk_bf16_f32 %0, %1, %2" : "=v"(u.i[2]) : "v"(b[0]), "v"(b[1]));
    asm("v_cvt_pk_bf16_f32 %0, %1, %2" : "=v"(u.i[3]) : "v"(b[2]), "v"(b[3]));
    return u.v;
}
#define GLDS(gp, lp) __builtin_amdgcn_global_load_lds( \
    (const __attribute__((address_space(1))) void*)(gp), \
    (__attribute__((address_space(3))) void*)(lp), 16, 0, 0)

// ---------------- weight reorder (once, tiny) ----------------
// Wcat_ch : chunk layout [c:0..31][n:0..640) ; k<128 -> W_l, else W_r.
// Wleaf_ch: chunk layout [c:0..39][n:0..256) ; k<300 valid else 0.
__global__ __launch_bounds__(256) void reorder_kernel(
    const float* __restrict__ W_l, const float* __restrict__ W_r,
    const float* __restrict__ W_leaf,
    short* __restrict__ Wcat_ch, short* __restrict__ Wleaf_ch)
{
    int idx = blockIdx.x * 256 + threadIdx.x;
    if (idx < 163840) {
        int n = idx >> 8, k = idx & 255;
        float v = (k < 128) ? W_l[k * 640 + n] : W_r[(k - 128) * 640 + n];
        Wcat_ch[(((size_t)(k >> 3)) * 640 + n) * 8 + (k & 7)] = f2bf(v);
        return;
    }
    idx -= 163840;
    if (idx < 81920) {
        int n = idx / 320, k = idx - n * 320;
        short v = (k < 300) ? f2bf(W_leaf[k * 256 + n]) : (short)0;
        Wleaf_ch[(((size_t)(k >> 3)) * 256 + n) * 8 + (k & 7)] = v;
    }
}

// ---------------- leaf: [32768,320fp32]@[320,256] + bias, split h/c ----------------
// 512 blocks x 64 rows (2 blocks/CU); each block computes ALL 256 cols.
// Wave w owns col-quarter [64w,64w+64). A: fp32 GLDS swizzled + pack8.
// B: bf16 WlfC via 8 GLDS/wave, b128 fragment reads.
__global__ __launch_bounds__(256) void leaf_kernel(
    const float* __restrict__ x,   const short* __restrict__ Bw,
    const float* __restrict__ bleaf,
    short* __restrict__ hD,       // level-1 A, chunk layout [32][16384] units
    short* __restrict__ cDb)      // bf16 col-blocked [8][32768][16]
{
    __shared__ float Als[64 * 64];      // 16 KB: [row][16 units], src-swizzled
    __shared__ short Bls[8 * 256 * 8];  // 32 KB: [c][n 0..256) units
    const int tid  = threadIdx.x;
    const int w    = tid >> 6, lane = tid & 63;
    const int quad = lane >> 4, l16 = lane & 15;
    const int mBlk = blockIdx.x * 64;
    const int waveN = w * 64;           // col-quarter

    f32x4 acc[4][4] = {};
    const f32x4 zero4 = {0.f, 0.f, 0.f, 0.f};

    for (int c = 0; c < 5; ++c) {           // K = 5 * 64 = 320 (300 + zero pad)
        const int k0c = c * 64;
        // ---- stage A (x) as fp32, XOR-swizzled source, linear LDS ----
        {
            const int q_lds = lane & 15;
            const int rsub  = lane >> 4;
            #pragma unroll
            for (int g = 0; g < 4; ++g) {
                int row = w * 16 + g * 4 + rsub;
                int q_g = (q_lds & 8) | ((q_lds & 7) ^ (row & 7));
                if (c < 4 || q_g < 11) {
                    GLDS(x + (size_t)(mBlk + row) * 300 + k0c + q_g * 4,
                         (char*)Als + (w * 16 + g * 4) * 256);
                } else {
                    *(f32x4*)((char*)Als + row * 256 + q_lds * 16) = zero4;  // pad k=300..319
                }
            }
        }
        // ---- stage B from WlfC: 8 GLDS/wave (2048 units) ----
        #pragma unroll
        for (int g = 0; g < 8; ++g) {
            int i   = w * 8 + g;                // 0..31
            int cc  = i >> 2, colg = (i & 3) * 64;
            GLDS(Bw + ((size_t)(c * 8 + cc) * 256 + colg + lane) * 8,
                 (char*)Bls + ((cc * 256 + colg)) * 16);
        }
        __syncthreads();
        #pragma unroll
        for (int ks = 0; ks < 2; ++ks) {
            const int ca = ks * 4 + quad;
            bfrag8 af[4], bf4[4];
            #pragma unroll
            for (int i = 0; i < 4; ++i) {
                int r  = i * 16 + l16;
                int u0 = 2 * ca, u1 = 2 * ca + 1;
                int s0 = (u0 & 8) | ((u0 & 7) ^ (r & 7));
                int s1 = (u1 & 8) | ((u1 & 7) ^ (r & 7));
                f32x4 a0 = *(const f32x4*)(Als + r * 64 + s0 * 4);
                f32x4 a1 = *(const f32x4*)(Als + r * 64 + s1 * 4);
                af[i] = pack8(a0, a1);
            }
            #pragma unroll
            for (int jn = 0; jn < 4; ++jn)
                bf4[jn] = *(const bfrag8*)(Bls + (ca * 256 + waveN + jn * 16 + l16) * 8);
            #pragma unroll
            for (int i = 0; i < 4; ++i)
                #pragma unroll
                for (int jn = 0; jn < 4; ++jn)
                    acc[i][jn] = __builtin_amdgcn_mfma_f32_16x16x32_bf16(
                                     af[i], bf4[jn], acc[i][jn], 0, 0, 0);
        }
        __syncthreads();
    }

    #pragma unroll
    for (int i = 0; i < 4; ++i) {
        int row0 = mBlk + i * 16 + quad * 4;
        #pragma unroll
        for (int jn = 0; jn < 4; ++jn) {
            int col = waveN + jn * 16 + l16;
            float bv = bleaf[col];
            #pragma unroll
            for (int rg = 0; rg < 4; ++rg) {
                float v = acc[i][jn][rg] + bv;
                int m = row0 + rg;
                if (col < 128) {
                    int hc = col;
                    hD[(((size_t)((m & 1) * 16 + (hc >> 3))) * 16384 + (m >> 1)) * 8
                       + (hc & 7)] = f2bf(v);
                } else {
                    int ch = col - 128;
                    cDb[(size_t)(ch >> 4) * 32768 * 16 + (size_t)m * 16 + (ch & 15)]
                        = f2bf(v);
                }
            }
        }
    }
}

// ---------------- weight-stationary level kernel (levels 1..8) ----------------
// PROVEN SHAPE: Wfr loaded ONCE at kernel scope. nst row-subtiles amortize.
// CIN_BF / COUT_BF select bf16 col-blocked c[j][rows][16] vs fp32 [rows][128].
template<int CIN_BF, int COUT_BF>
__global__ __launch_bounds__(256, 2) void level_ws_t(
    const short* __restrict__ A,      // [32][M] chunk units
    const void*  __restrict__ cprev,  // 2M rows
    const short* __restrict__ Wch,    // [32][640] chunk units
    const float* __restrict__ bias,   // [640]
    short* __restrict__ hout, void* __restrict__ cout_,  // M rows
    int M, int nst)
{
    __shared__ short Als[32 * 64 * 8];   // 32 KB, [c][row]
    const int tid  = threadIdx.x;
    const int w    = tid >> 6, lane = tid & 63;
    const int quad = lane >> 4, l16 = lane & 15;
    const int j   = blockIdx.y;
    const int tb0 = blockIdx.x * 64 * nst;
    const int h   = j * 16 + l16;

    // stage subtile 0 (overlaps the Wfr loads below)
    #pragma unroll
    for (int s = 0; s < 8; ++s)
        GLDS(A + ((size_t)(s * 4 + w) * M + tb0 + lane) * 8,
             (char*)Als + (s * 4 + w) * 1024);

    bfrag8 Wfr[5][8];
    #pragma unroll
    for (int g = 0; g < 5; ++g)
        #pragma unroll
        for (int s = 0; s < 8; ++s)
            Wfr[g][s] = *(const bfrag8*)(Wch + ((size_t)(s * 4 + quad) * 640
                                                + g * 128 + h) * 8);
    const float bi  = bias[h],       bfl = bias[128 + h], bfr_ = bias[256 + h];
    const float bo  = bias[384 + h], bg  = bias[512 + h];

    const int Mn = M >> 1;
    for (int st = 0; st < nst; ++st) {
        const int tb = tb0 + st * 64;
        __syncthreads();                 // staging of subtile st complete

        f32x4 acc[5] = {};
        #pragma unroll
        for (int s = 0; s < 8; ++s) {
            bfrag8 af = *(const bfrag8*)(Als + ((s * 4 + quad) * 64 + w * 16 + l16) * 8);
            #pragma unroll
            for (int g = 0; g < 5; ++g)
                acc[g] = __builtin_amdgcn_mfma_f32_16x16x32_bf16(af, Wfr[g][s], acc[g], 0, 0, 0);
        }

        if (st + 1 < nst) {
            __syncthreads();             // all Als reads done; restage
            #pragma unroll
            for (int s = 0; s < 8; ++s)
                GLDS(A + ((size_t)(s * 4 + w) * M + tb + 64 + lane) * 8,
                     (char*)Als + (s * 4 + w) * 1024);
        }

        #pragma unroll
        for (int rg = 0; rg < 4; ++rg) {
            int m = tb + w * 16 + quad * 4 + rg;
            float gi  = acc[0][rg] + bi;
            float gfl = acc[1][rg] + bfl;
            float gfr = acc[2][rg] + bfr_;
            float go  = acc[3][rg] + bo;
            float gg  = acc[4][rg] + bg;
            float cl, cr;
            if (CIN_BF) {
                const short* cp = (const short*)cprev;
                size_t base = (size_t)(h >> 4) * ((size_t)2 * M) * 16
                              + (size_t)(2 * m) * 16 + (h & 15);
                cl = bf2f(cp[base]);
                cr = bf2f(cp[base + 16]);
            } else {
                const float* cp = (const float*)cprev;
                cl = cp[(size_t)(2 * m) * 128 + h];
                cr = cp[(size_t)(2 * m + 1) * 128 + h];
            }
            float cn  = sigf(gfl) * cl + sigf(gfr) * cr + sigf(gi) * tanh_f(gg);
            float hn  = sigf(go) * tanh_f(cn);
            hout[(((size_t)((m & 1) * 16 + (h >> 3))) * Mn + (m >> 1)) * 8
                 + (h & 7)] = f2bf(hn);
            if (COUT_BF) {
                ((short*)cout_)[(size_t)(h >> 4) * (size_t)M * 16
                                + (size_t)m * 16 + (h & 15)] = f2bf(cn);
            } else {
                ((float*)cout_)[(size_t)m * 128 + h] = cn;
            }
        }
    }
}

// ---------------- single-block finisher: levels 9..12 ----------------
__global__ __launch_bounds__(512) void finish_kernel(
    const short* __restrict__ hin,   // [32][64] units (128-row chunk layout)
    const float* __restrict__ cin,   // [128][128] f32
    const short* __restrict__ Wch, const float* __restrict__ bias,
    float* __restrict__ out)         // [8][128]
{
    __shared__ short hP[32 * 64 * 8];   // 32 KB ping
    __shared__ short hQ[32 * 32 * 8];   // 16 KB pong
    __shared__ float cA[128 * 128];     // 64 KB
    __shared__ float cB[64 * 128];      // 32 KB
    const int tid  = threadIdx.x;
    const int w    = tid >> 6, lane = tid & 63;
    const int quad = lane >> 4, l16 = lane & 15;
    const int h    = w * 16 + l16;      // wave = h-group

    #pragma unroll
    for (int g = 0; g < 4; ++g)
        GLDS(hin + ((size_t)((g * 8 + w) * 64 + lane)) * 8,
             (char*)hP + ((g * 8 + w) * 64) * 16);
    #pragma unroll
    for (int g = 0; g < 8; ++g)
        GLDS(cin + ((size_t)((g * 8 + w) * 64 + lane)) * 4,
             (char*)cA + ((g * 8 + w) * 64) * 16);

    bfrag8 Wfr[5][8];
    #pragma unroll
    for (int g = 0; g < 5; ++g)
        #pragma unroll
        for (int s = 0; s < 8; ++s)
            Wfr[g][s] = *(const bfrag8*)(Wch + ((size_t)(s * 4 + quad) * 640
                                                + g * 128 + h) * 8);
    const float bi  = bias[h],       bfl = bias[128 + h], bfr_ = bias[256 + h];
    const float bo  = bias[384 + h], bg  = bias[512 + h];

    __syncthreads();

    #pragma unroll
    for (int t = 0; t < 4; ++t) {              // levels 9..12
        const int Mo = 64 >> t;                // 64, 32, 16, 8
        const short* hsrc = (t & 1) ? hQ : hP;
        short* hdst       = (t & 1) ? hP : hQ;
        const float* cread  = (t & 1) ? cB : cA;
        float*       cwrite = (t & 1) ? cA : cB;
        const int nrt = (Mo + 15) >> 4;

        for (int rt = 0; rt < nrt; ++rt) {
            f32x4 acc[5] = {};
            #pragma unroll
            for (int s = 0; s < 8; ++s) {
                bfrag8 af = *(const bfrag8*)(hsrc + ((s * 4 + quad) * Mo
                                                     + rt * 16 + l16) * 8);
                #pragma unroll
                for (int g = 0; g < 5; ++g)
                    acc[g] = __builtin_amdgcn_mfma_f32_16x16x32_bf16(
                                 af, Wfr[g][s], acc[g], 0, 0, 0);
            }
            #pragma unroll
            for (int rg = 0; rg < 4; ++rg) {
                int m = rt * 16 + quad * 4 + rg;
                if (m < Mo) {
                    float gi  = acc[0][rg] + bi;
                    float gfl = acc[1][rg] + bfl;
                    float gfr = acc[2][rg] + bfr_;
                    float go  = acc[3][rg] + bo;
                    float gg  = acc[4][rg] + bg;
                    float cl  = cread[(2 * m) * 128 + h];
                    float cr  = cread[(2 * m + 1) * 128 + h];
                    float cn  = sigf(gfl) * cl + sigf(gfr) * cr + sigf(gi) * tanh_f(gg);
                    float hn  = sigf(go) * tanh_f(cn);
                    if (t == 3) {
                        out[(size_t)m * 128 + h] = hn;
                    } else {
                        hdst[(((m & 1) * 16 + (h >> 3)) * (Mo >> 1) + (m >> 1)) * 8
                             + (h & 7)] = f2bf(hn);
                        cwrite[m * 128 + h] = cn;
                    }
                }
            }
        }
        __syncthreads();
    }
}

extern "C" void kernel_launch(void* const* d_in, const int* in_sizes, int n_in,
                              void* d_out, int out_size, void* d_ws, size_t ws_size,
                              hipStream_t stream)
{
    const float* x      = (const float*)d_in[0];
    const float* W_leaf = (const float*)d_in[1];
    const float* b_leaf = (const float*)d_in[2];
    const float* W_l    = (const float*)d_in[3];
    const float* W_r    = (const float*)d_in[4];
    const float* b      = (const float*)d_in[5];
    float* out = (float*)d_out;

    // workspace (~38.4 MB)
    char* p = (char*)d_ws;
    short* hA    = (short*)p; p += (size_t)32 * 16384 * 16 + 1024; //  8.4 MB
    short* hB    = (short*)p; p += (size_t)32 * 8192 * 16 + 1024;  //  4.2 MB
    char*  c0    = p;         p += (size_t)32768 * 128 * 4;        // 16.8 MB
    char*  c1    = p;         p += (size_t)16384 * 128 * 4;        //  8.4 MB
    short* WcatC = (short*)p; p += (size_t)32 * 640 * 16;          // 320 KB
    short* WlfC  = (short*)p; p += (size_t)40 * 256 * 16;          // 160 KB

    // 1) reorder: WcatC + bf16 WlfC (tiny)
    reorder_kernel<<<960, 256, 0, stream>>>(W_l, W_r, W_leaf, WcatC, WlfC);

    // 2) leaf: 512 blocks x 64 rows; h -> hA, c -> c0 bf16 col-blocked
    leaf_kernel<<<512, 256, 0, stream>>>(x, WlfC, b_leaf, hA, (short*)c0);

    // 3) lev1: cin bf16 (c0), cout bf16 (c1); M=16384, nst=4
    level_ws_t<1, 1><<<dim3(16384 / 256, 8), 256, 0, stream>>>(
        hA, c0, WcatC, b, hB, c1, 16384, 4);
    // 4) lev2: cin bf16 (c1), cout fp32 (c0); M=8192, nst=2
    level_ws_t<1, 0><<<dim3(8192 / 128, 8), 256, 0, stream>>>(
        hB, c1, WcatC, b, hA, c0, 8192, 2);

    // 5..10) levels 3..8 fp32 c; lev3 nst=2, rest nst=1
    const short* hin = hA; const char* cin = c0;
    int M = 4096;
    for (int lev = 3; lev <= 8; ++lev) {
        short* ho = (lev & 1) ? hB : hA;
        char*  co = (lev & 1) ? c1 : c0;
        int nst = (lev == 3) ? 2 : 1;
        level_ws_t<0, 0><<<dim3(M / (64 * nst), 8), 256, 0, stream>>>(
            hin, cin, WcatC, b, ho, co, M, nst);
        hin = ho; cin = co;
        M >>= 1;
    }
    // after lev8: hin = hA ([32][64] units), cin = c0 ([128][128] fp32)

    // 11) levels 9..12: single-block finisher
    finish_kernel<<<1, 512, 0, stream>>>(hA, (const float*)c0, WcatC, b, out);
}